// Round 5
// baseline (3762.202 us; speedup 1.0000x reference)
//
#include <hip/hip_runtime.h>

#define DT 0.1f
#define NSTEPS 10

typedef float v2f __attribute__((ext_vector_type(2)));

#if __has_builtin(__builtin_amdgcn_exp2f)
#define EXP2(x) __builtin_amdgcn_exp2f(x)
#else
#define EXP2(x) exp2f(x)
#endif

#if __has_builtin(__builtin_amdgcn_rcpf)
#define RCP(x) __builtin_amdgcn_rcpf(x)
#else
#define RCP(x) (1.0f / (x))
#endif

#if __has_builtin(__builtin_amdgcn_sqrtf)
#define SQRTF(x) __builtin_amdgcn_sqrtf(x)
#else
#define SQRTF(x) sqrtf(x)
#endif

static __device__ __forceinline__ v2f splat(float s) { v2f r; r.x = s; r.y = s; return r; }

static __device__ __forceinline__ v2f vfma(v2f a, v2f b, v2f c) {
    return __builtin_elementwise_fma(a, b, c);
}

// tanh of two independent values packed in a v2f (exp-based).
// tanh(x) = 1 - 2/(e^{2x}+1). Clamp keeps the shared-rcp product finite.
static __device__ __forceinline__ v2f tanh_pair(v2f x) {
    v2f xc = __builtin_elementwise_min(__builtin_elementwise_max(x, splat(-10.0f)), splat(10.0f));
    v2f t = xc * splat(-2.8853900818f);   // -2*log2(e)
    float e0 = EXP2(t.x);
    float e1 = EXP2(t.y);
    float d0 = e0 + 1.0f;
    float d1 = e1 + 1.0f;
    float r = RCP(d0 * d1);
    v2f inv; inv.x = r * d1; inv.y = r * d0;
    return vfma(inv, splat(2.0f), splat(-1.0f));  // 2*inv - 1
}

// LDS weight block layout (per policy, 132-float stride):
//   w1: +0 (32), b1: +32 (8), w2: +40 (64), b2: +104 (8), w3: +112 (16), b3: +128 (2)
#define P_W1 0
#define P_B1 32
#define P_W2 40
#define P_B2 104
#define P_W3 112
#define P_B3 128
#define P_STRIDE 132

// tanh-MLP 4->8->8->2 on a pair of rows; weights from LDS.
static __device__ __forceinline__ void policy_pair(
    const float* w,   // LDS base for this policy
    v2f c0, v2f c1, v2f c2, v2f c3,
    v2f& o0, v2f& o1)
{
    v2f h[8];
#pragma unroll
    for (int j = 0; j < 8; ++j) {
        v2f a = vfma(splat(w[P_W1 + j * 4 + 0]), c0, splat(w[P_B1 + j]));
        a = vfma(splat(w[P_W1 + j * 4 + 1]), c1, a);
        a = vfma(splat(w[P_W1 + j * 4 + 2]), c2, a);
        a = vfma(splat(w[P_W1 + j * 4 + 3]), c3, a);
        h[j] = tanh_pair(a);
    }
    v2f g[8];
#pragma unroll
    for (int j = 0; j < 8; ++j) {
        v2f a = vfma(splat(w[P_W2 + j * 8 + 0]), h[0], splat(w[P_B2 + j]));
#pragma unroll
        for (int k = 1; k < 8; ++k) a = vfma(splat(w[P_W2 + j * 8 + k]), h[k], a);
        g[j] = tanh_pair(a);
    }
    v2f t0 = vfma(splat(w[P_W3 + 0]), g[0], splat(w[P_B3 + 0]));
    v2f t1 = vfma(splat(w[P_W3 + 8]), g[0], splat(w[P_B3 + 1]));
#pragma unroll
    for (int k = 1; k < 8; ++k) {
        t0 = vfma(splat(w[P_W3 + k]), g[k], t0);
        t1 = vfma(splat(w[P_W3 + 8 + k]), g[k], t1);
    }
    o0 = t0;
    o1 = t1;
}

__global__ void __launch_bounds__(256) rollout_kernel(
    const float* __restrict__ s_star, const float* __restrict__ s0,
    const float* __restrict__ fc1_w, const float* __restrict__ fc1_b,
    const float* __restrict__ fc2_w, const float* __restrict__ fc2_b,
    const float* __restrict__ rc1_w, const float* __restrict__ rc1_b,
    const float* __restrict__ rc2_w, const float* __restrict__ rc2_b,
    const float* __restrict__ rc3_w, const float* __restrict__ rc3_b,
    const float* __restrict__ rr1_w, const float* __restrict__ rr1_b,
    const float* __restrict__ rr2_w, const float* __restrict__ rr2_b,
    const float* __restrict__ rr3_w, const float* __restrict__ rr3_b,
    float* __restrict__ out, int NQ)  // NQ = number of row-quads
{
    __shared__ float lw[2 * P_STRIDE];

    int tid = threadIdx.x;
    if (tid < 130) {
        float vrr, vrc;
        if (tid < 32)       { vrr = rr1_w[tid];       vrc = rc1_w[tid]; }
        else if (tid < 40)  { vrr = rr1_b[tid - 32];  vrc = rc1_b[tid - 32]; }
        else if (tid < 104) { vrr = rr2_w[tid - 40];  vrc = rc2_w[tid - 40]; }
        else if (tid < 112) { vrr = rr2_b[tid - 104]; vrc = rc2_b[tid - 104]; }
        else if (tid < 128) { vrr = rr3_w[tid - 112]; vrc = rc3_w[tid - 112]; }
        else                { vrr = rr3_b[tid - 128]; vrc = rc3_b[tid - 128]; }
        lw[tid] = vrr;
        lw[P_STRIDE + tid] = vrc;
    }
    __syncthreads();

    int i = blockIdx.x * blockDim.x + threadIdx.x;
    if (i >= NQ) return;

    // rows 4i..4i+3
    float4 ssA = reinterpret_cast<const float4*>(s_star)[2 * i];
    float4 ssB = reinterpret_cast<const float4*>(s_star)[2 * i + 1];
    float4 svA = reinterpret_cast<const float4*>(s0)[2 * i];
    float4 svB = reinterpret_cast<const float4*>(s0)[2 * i + 1];

    v2f ssx[2], ssy[2], sx[2], sy[2];
    ssx[0].x = ssA.x; ssx[0].y = ssA.z; ssy[0].x = ssA.y; ssy[0].y = ssA.w;
    ssx[1].x = ssB.x; ssx[1].y = ssB.z; ssy[1].x = ssB.y; ssy[1].y = ssB.w;
    sx[0].x = svA.x;  sx[0].y = svA.z;  sy[0].x = svA.y;  sy[0].y = svA.w;
    sx[1].x = svB.x;  sx[1].y = svB.z;  sy[1].x = svB.y;  sy[1].y = svB.w;

    // Fuse linear predictor ah = fc2(fc1(x)) = A @ [s, s_star] + cb  (uniform A, cb)
    float A[2][4];
    float cb[2];
#pragma unroll
    for (int r = 0; r < 2; ++r) {
#pragma unroll
        for (int c = 0; c < 4; ++c) {
            float a = 0.0f;
#pragma unroll
            for (int j = 0; j < 4; ++j)
                a = fmaf(fc2_w[r * 4 + j], fc1_w[j * 4 + c], a);
            A[r][c] = a;
        }
        float b = fc2_b[r];
#pragma unroll
        for (int j = 0; j < 4; ++j) b = fmaf(fc2_w[r * 4 + j], fc1_b[j], b);
        cb[r] = b;
    }

    v2f d0[2], d1[2], ahs0[2], err[2];
#pragma unroll
    for (int p = 0; p < 2; ++p) {
        d0[p] = vfma(splat(A[0][2]), ssx[p], vfma(splat(A[0][3]), ssy[p], splat(cb[0])));
        d1[p] = vfma(splat(A[1][2]), ssx[p], vfma(splat(A[1][3]), ssy[p], splat(cb[1])));
        ahs0[p].x = (ssx[p].x > 0.5f) ? -1.0f : 1.0f;
        ahs0[p].y = (ssx[p].y > 0.5f) ? -1.0f : 1.0f;
        err[p] = splat(0.0f);
    }

#pragma unroll 1
    for (int t = 0; t < NSTEPS; ++t) {
        v2f ah0[2], ah1[2], arr0[2], arr1[2], ar0[2], ar1[2];
#pragma unroll
        for (int p = 0; p < 2; ++p) {
            ah0[p] = vfma(splat(A[0][0]), sx[p], vfma(splat(A[0][1]), sy[p], d0[p]));
            ah1[p] = vfma(splat(A[1][0]), sx[p], vfma(splat(A[1][1]), sy[p], d1[p]));
        }
        // rr,rr then rc,rc: each LDS weight read feeds both pairs back-to-back
        policy_pair(&lw[0],        sx[0], sy[0], ah0[0], ah1[0], arr0[0], arr1[0]);
        policy_pair(&lw[0],        sx[1], sy[1], ah0[1], ah1[1], arr0[1], arr1[1]);
        policy_pair(&lw[P_STRIDE], sx[0], sy[0], ah0[0], ah1[0], ar0[0], ar1[0]);
        policy_pair(&lw[P_STRIDE], sx[1], sy[1], ah0[1], ah1[1], ar0[1], ar1[1]);

#pragma unroll
        for (int p = 0; p < 2; ++p) {
            sx[p] = vfma(splat(DT), ar0[p], sx[p]);
            sy[p] = vfma(splat(DT), ar1[p], sy[p]);

            v2f dx = ssx[p] - sx[p], dy = ssy[p] - sy[p];
            v2f n1 = vfma(dx, dx, dy * dy);
            v2f ux = arr0[p] - ar0[p], uy = arr1[p] - ar1[p];
            v2f n2 = vfma(ux, ux, uy * uy);
            v2f vx = ahs0[p] - ah0[p];
            v2f n3 = vfma(vx, vx, ah1[p] * ah1[p]);

            v2f e1; e1.x = SQRTF(n1.x); e1.y = SQRTF(n1.y);
            v2f e2; e2.x = SQRTF(n2.x); e2.y = SQRTF(n2.y);
            v2f e3; e3.x = SQRTF(n3.x); e3.y = SQRTF(n3.y);

            err[p] = err[p] + e1;
            err[p] = vfma(splat(0.1f), e2, err[p]);
            err[p] = err[p] + e3;
        }
    }

    float4 o;
    o.x = err[0].x; o.y = err[0].y; o.z = err[1].x; o.w = err[1].y;
    reinterpret_cast<float4*>(out)[i] = o;
}

extern "C" void kernel_launch(void* const* d_in, const int* in_sizes, int n_in,
                              void* d_out, int out_size, void* d_ws, size_t ws_size,
                              hipStream_t stream) {
    const float* s_star = (const float*)d_in[0];
    const float* s0     = (const float*)d_in[1];
    const float* fc1_w  = (const float*)d_in[2];
    const float* fc1_b  = (const float*)d_in[3];
    const float* fc2_w  = (const float*)d_in[4];
    const float* fc2_b  = (const float*)d_in[5];
    const float* rc1_w  = (const float*)d_in[6];
    const float* rc1_b  = (const float*)d_in[7];
    const float* rc2_w  = (const float*)d_in[8];
    const float* rc2_b  = (const float*)d_in[9];
    const float* rc3_w  = (const float*)d_in[10];
    const float* rc3_b  = (const float*)d_in[11];
    const float* rr1_w  = (const float*)d_in[12];
    const float* rr1_b  = (const float*)d_in[13];
    const float* rr2_w  = (const float*)d_in[14];
    const float* rr2_b  = (const float*)d_in[15];
    const float* rr3_w  = (const float*)d_in[16];
    const float* rr3_b  = (const float*)d_in[17];
    float* out = (float*)d_out;

    int B = in_sizes[0] / 2;   // rows
    int NQ = B / 4;            // row-quads (B = 4194304)
    int block = 256;
    int grid = (NQ + block - 1) / block;
    rollout_kernel<<<grid, block, 0, stream>>>(
        s_star, s0, fc1_w, fc1_b, fc2_w, fc2_b,
        rc1_w, rc1_b, rc2_w, rc2_b, rc3_w, rc3_b,
        rr1_w, rr1_b, rr2_w, rr2_b, rr3_w, rr3_b,
        out, NQ);
}

// Round 6
// 610.840 us; speedup vs baseline: 6.1591x; 6.1591x over previous
//
#include <hip/hip_runtime.h>

#define DT 0.1f
#define NSTEPS 10

typedef float v2f __attribute__((ext_vector_type(2)));

#if __has_builtin(__builtin_amdgcn_exp2f)
#define EXP2(x) __builtin_amdgcn_exp2f(x)
#else
#define EXP2(x) exp2f(x)
#endif

#if __has_builtin(__builtin_amdgcn_rcpf)
#define RCP(x) __builtin_amdgcn_rcpf(x)
#else
#define RCP(x) (1.0f / (x))
#endif

#if __has_builtin(__builtin_amdgcn_sqrtf)
#define SQRTF(x) __builtin_amdgcn_sqrtf(x)
#else
#define SQRTF(x) sqrtf(x)
#endif

static __device__ __forceinline__ v2f splat(float s) { v2f r; r.x = s; r.y = s; return r; }

static __device__ __forceinline__ v2f vfma(v2f a, v2f b, v2f c) {
    return __builtin_elementwise_fma(a, b, c);
}

// tanh of two independent values packed in a v2f (exp-based).
// tanh(x) = 1 - 2/(e^{2x}+1). Clamp keeps the shared-rcp product finite.
static __device__ __forceinline__ v2f tanh_pair(v2f x) {
    v2f xc = __builtin_elementwise_min(__builtin_elementwise_max(x, splat(-10.0f)), splat(10.0f));
    v2f t = xc * splat(-2.8853900818f);   // -2*log2(e)
    float e0 = EXP2(t.x);
    float e1 = EXP2(t.y);
    float d0 = e0 + 1.0f;
    float d1 = e1 + 1.0f;
    float r = RCP(d0 * d1);
    v2f inv; inv.x = r * d1; inv.y = r * d0;
    return vfma(inv, splat(2.0f), splat(-1.0f));  // 2*inv - 1
}

// tanh-MLP 4->8->8->2 on a pair of rows (packed in v2f lanes).
static __device__ __forceinline__ void policy_pair(
    const float* __restrict__ w1, const float* __restrict__ b1,
    const float* __restrict__ w2, const float* __restrict__ b2,
    const float* __restrict__ w3, const float* __restrict__ b3,
    v2f c0, v2f c1, v2f c2, v2f c3,
    v2f& o0, v2f& o1)
{
    v2f h[8];
#pragma unroll
    for (int j = 0; j < 8; ++j) {
        v2f a = vfma(splat(w1[j * 4 + 0]), c0, splat(b1[j]));
        a = vfma(splat(w1[j * 4 + 1]), c1, a);
        a = vfma(splat(w1[j * 4 + 2]), c2, a);
        a = vfma(splat(w1[j * 4 + 3]), c3, a);
        h[j] = tanh_pair(a);
    }
    v2f g[8];
#pragma unroll
    for (int j = 0; j < 8; ++j) {
        v2f a = vfma(splat(w2[j * 8 + 0]), h[0], splat(b2[j]));
#pragma unroll
        for (int k = 1; k < 8; ++k) a = vfma(splat(w2[j * 8 + k]), h[k], a);
        g[j] = tanh_pair(a);
    }
    v2f t0 = vfma(splat(w3[0]), g[0], splat(b3[0]));
    v2f t1 = vfma(splat(w3[8]), g[0], splat(b3[1]));
#pragma unroll
    for (int k = 1; k < 8; ++k) {
        t0 = vfma(splat(w3[k]), g[k], t0);
        t1 = vfma(splat(w3[8 + k]), g[k], t1);
    }
    o0 = t0;
    o1 = t1;
}

__global__ void __launch_bounds__(256) rollout_kernel(
    const float* __restrict__ s_star, const float* __restrict__ s0,
    const float* __restrict__ fc1_w, const float* __restrict__ fc1_b,
    const float* __restrict__ fc2_w, const float* __restrict__ fc2_b,
    const float* __restrict__ rc1_w, const float* __restrict__ rc1_b,
    const float* __restrict__ rc2_w, const float* __restrict__ rc2_b,
    const float* __restrict__ rc3_w, const float* __restrict__ rc3_b,
    const float* __restrict__ rr1_w, const float* __restrict__ rr1_b,
    const float* __restrict__ rr2_w, const float* __restrict__ rr2_b,
    const float* __restrict__ rr3_w, const float* __restrict__ rr3_b,
    float* __restrict__ out, int NQ)  // NQ = number of row-quads
{
    int i = blockIdx.x * blockDim.x + threadIdx.x;
    if (i >= NQ) return;

    // rows 4i..4i+3
    float4 ssA = reinterpret_cast<const float4*>(s_star)[2 * i];
    float4 ssB = reinterpret_cast<const float4*>(s_star)[2 * i + 1];
    float4 svA = reinterpret_cast<const float4*>(s0)[2 * i];
    float4 svB = reinterpret_cast<const float4*>(s0)[2 * i + 1];

    v2f ssx[2], ssy[2], sx[2], sy[2];
    ssx[0].x = ssA.x; ssx[0].y = ssA.z; ssy[0].x = ssA.y; ssy[0].y = ssA.w;
    ssx[1].x = ssB.x; ssx[1].y = ssB.z; ssy[1].x = ssB.y; ssy[1].y = ssB.w;
    sx[0].x = svA.x;  sx[0].y = svA.z;  sy[0].x = svA.y;  sy[0].y = svA.w;
    sx[1].x = svB.x;  sx[1].y = svB.z;  sy[1].x = svB.y;  sy[1].y = svB.w;

    // Fuse linear predictor ah = fc2(fc1(x)) = A @ [s, s_star] + cb  (uniform A, cb)
    float A[2][4];
    float cb[2];
#pragma unroll
    for (int r = 0; r < 2; ++r) {
#pragma unroll
        for (int c = 0; c < 4; ++c) {
            float a = 0.0f;
#pragma unroll
            for (int j = 0; j < 4; ++j)
                a = fmaf(fc2_w[r * 4 + j], fc1_w[j * 4 + c], a);
            A[r][c] = a;
        }
        float b = fc2_b[r];
#pragma unroll
        for (int j = 0; j < 4; ++j) b = fmaf(fc2_w[r * 4 + j], fc1_b[j], b);
        cb[r] = b;
    }

    v2f d0[2], d1[2], ahs0[2], err[2];
#pragma unroll
    for (int p = 0; p < 2; ++p) {
        d0[p] = vfma(splat(A[0][2]), ssx[p], vfma(splat(A[0][3]), ssy[p], splat(cb[0])));
        d1[p] = vfma(splat(A[1][2]), ssx[p], vfma(splat(A[1][3]), ssy[p], splat(cb[1])));
        ahs0[p].x = (ssx[p].x > 0.5f) ? -1.0f : 1.0f;
        ahs0[p].y = (ssx[p].y > 0.5f) ? -1.0f : 1.0f;
        err[p] = splat(0.0f);
    }

#pragma unroll 2
    for (int t = 0; t < NSTEPS; ++t) {
        v2f ah0[2], ah1[2], arr0[2], arr1[2], ar0[2], ar1[2];
#pragma unroll
        for (int p = 0; p < 2; ++p) {
            ah0[p] = vfma(splat(A[0][0]), sx[p], vfma(splat(A[0][1]), sy[p], d0[p]));
            ah1[p] = vfma(splat(A[1][0]), sx[p], vfma(splat(A[1][1]), sy[p], d1[p]));
        }
        // order rr,rr then rc,rc so each weight value is reused back-to-back
        policy_pair(rr1_w, rr1_b, rr2_w, rr2_b, rr3_w, rr3_b,
                    sx[0], sy[0], ah0[0], ah1[0], arr0[0], arr1[0]);
        policy_pair(rr1_w, rr1_b, rr2_w, rr2_b, rr3_w, rr3_b,
                    sx[1], sy[1], ah0[1], ah1[1], arr0[1], arr1[1]);
        policy_pair(rc1_w, rc1_b, rc2_w, rc2_b, rc3_w, rc3_b,
                    sx[0], sy[0], ah0[0], ah1[0], ar0[0], ar1[0]);
        policy_pair(rc1_w, rc1_b, rc2_w, rc2_b, rc3_w, rc3_b,
                    sx[1], sy[1], ah0[1], ah1[1], ar0[1], ar1[1]);

#pragma unroll
        for (int p = 0; p < 2; ++p) {
            sx[p] = vfma(splat(DT), ar0[p], sx[p]);
            sy[p] = vfma(splat(DT), ar1[p], sy[p]);

            v2f dx = ssx[p] - sx[p], dy = ssy[p] - sy[p];
            v2f n1 = vfma(dx, dx, dy * dy);
            v2f ux = arr0[p] - ar0[p], uy = arr1[p] - ar1[p];
            v2f n2 = vfma(ux, ux, uy * uy);
            v2f vx = ahs0[p] - ah0[p];
            v2f n3 = vfma(vx, vx, ah1[p] * ah1[p]);

            v2f e1; e1.x = SQRTF(n1.x); e1.y = SQRTF(n1.y);
            v2f e2; e2.x = SQRTF(n2.x); e2.y = SQRTF(n2.y);
            v2f e3; e3.x = SQRTF(n3.x); e3.y = SQRTF(n3.y);

            err[p] = err[p] + e1;
            err[p] = vfma(splat(0.1f), e2, err[p]);
            err[p] = err[p] + e3;
        }
    }

    float4 o;
    o.x = err[0].x; o.y = err[0].y; o.z = err[1].x; o.w = err[1].y;
    reinterpret_cast<float4*>(out)[i] = o;
}

extern "C" void kernel_launch(void* const* d_in, const int* in_sizes, int n_in,
                              void* d_out, int out_size, void* d_ws, size_t ws_size,
                              hipStream_t stream) {
    const float* s_star = (const float*)d_in[0];
    const float* s0     = (const float*)d_in[1];
    const float* fc1_w  = (const float*)d_in[2];
    const float* fc1_b  = (const float*)d_in[3];
    const float* fc2_w  = (const float*)d_in[4];
    const float* fc2_b  = (const float*)d_in[5];
    const float* rc1_w  = (const float*)d_in[6];
    const float* rc1_b  = (const float*)d_in[7];
    const float* rc2_w  = (const float*)d_in[8];
    const float* rc2_b  = (const float*)d_in[9];
    const float* rc3_w  = (const float*)d_in[10];
    const float* rc3_b  = (const float*)d_in[11];
    const float* rr1_w  = (const float*)d_in[12];
    const float* rr1_b  = (const float*)d_in[13];
    const float* rr2_w  = (const float*)d_in[14];
    const float* rr2_b  = (const float*)d_in[15];
    const float* rr3_w  = (const float*)d_in[16];
    const float* rr3_b  = (const float*)d_in[17];
    float* out = (float*)d_out;

    int B = in_sizes[0] / 2;   // rows
    int NQ = B / 4;            // row-quads (B = 4194304)
    int block = 256;
    int grid = (NQ + block - 1) / block;
    rollout_kernel<<<grid, block, 0, stream>>>(
        s_star, s0, fc1_w, fc1_b, fc2_w, fc2_b,
        rc1_w, rc1_b, rc2_w, rc2_b, rc3_w, rc3_b,
        rr1_w, rr1_b, rr2_w, rr2_b, rr3_w, rr3_b,
        out, NQ);
}